// Round 8
// baseline (494.810 us; speedup 1.0000x reference)
//
#include <hip/hip_runtime.h>
#include <hip/hip_bf16.h>

#define NN 100000
#define EE 1600000

constexpr int SCAN_BLK = 1024;                       // elements per scan block (256 thr * 4)
constexpr int NB_SCAN  = (NN + SCAN_BLK - 1) / SCAN_BLK;  // 98

// Range-partitioned CSR build: 8 dst-ranges
constexpr int NR  = 8;
constexpr int RS  = NN / NR;        // 12500 nodes per range
constexpr int CB  = 200;            // edge chunks
constexpr int CE  = EE / CB;        // 8000 edges per chunk (exact)

// ---------------- CSR build ----------------

__global__ void zero_int(int* __restrict__ p, int n) {
    int i = blockIdx.x * 256 + threadIdx.x;
    if (i < n) p[i] = 0;
}

// blockIdx = chunk*NR + r. 4-edge batched: d[4]/s[4] loaded upfront (coalesced,
// unconditional), then 4 independent predicated atomics -> MLP 4.
__global__ __launch_bounds__(256) void hist_k(const int* __restrict__ ei, int* __restrict__ deg) {
    int r = blockIdx.x % NR, chunk = blockIdx.x / NR;
    int lo = r * RS, hi = lo + RS;
    const int* __restrict__ dstp = ei + EE;
    int base = chunk * CE;
    int tid = threadIdx.x;
    for (int ii = 0; ii < CE; ii += 1024) {
        int d[4], s[4];
        #pragma unroll
        for (int k = 0; k < 4; ++k) {
            int off = ii + tid + k * 256;
            int i = base + off;
            d[k] = (off < CE) ? dstp[i] : -1;
            s[k] = (off < CE) ? ei[i]   : -1;
        }
        #pragma unroll
        for (int k = 0; k < 4; ++k) {
            if (d[k] >= lo && d[k] < hi && s[k] != d[k])
                atomicAdd(&deg[d[k]], 1);
        }
    }
}

__global__ void sum_blocks(const int* __restrict__ deg, int* __restrict__ partials) {
    __shared__ int sh[256];
    int t = threadIdx.x;
    int base = blockIdx.x * SCAN_BLK + t * 4;
    int s = 0;
    #pragma unroll
    for (int k = 0; k < 4; ++k) { int i = base + k; if (i < NN) s += deg[i]; }
    sh[t] = s; __syncthreads();
    for (int off = 128; off > 0; off >>= 1) {
        if (t < off) sh[t] += sh[t + off];
        __syncthreads();
    }
    if (t == 0) partials[blockIdx.x] = sh[0];
}

__global__ void scan_partials(int* __restrict__ partials) {
    __shared__ int sh[128];
    int t = threadIdx.x;
    int v = (t < NB_SCAN) ? partials[t] : 0;
    sh[t] = v;
    __syncthreads();
    for (int off = 1; off < 128; off <<= 1) {
        int tmp = (t >= off) ? sh[t - off] : 0;
        __syncthreads();
        sh[t] += tmp;
        __syncthreads();
    }
    if (t < NB_SCAN) partials[t] = sh[t] - v;   // exclusive prefix
}

__global__ void scan_final(const int* __restrict__ deg, const int* __restrict__ partials,
                           int* __restrict__ rowptr, int* __restrict__ cursor) {
    __shared__ int sh[256];
    int t = threadIdx.x;
    int base = blockIdx.x * SCAN_BLK + t * 4;
    int v[4]; int s = 0;
    #pragma unroll
    for (int k = 0; k < 4; ++k) { int i = base + k; v[k] = (i < NN) ? deg[i] : 0; s += v[k]; }
    sh[t] = s; __syncthreads();
    for (int off = 1; off < 256; off <<= 1) {
        int tmp = (t >= off) ? sh[t - off] : 0;
        __syncthreads();
        sh[t] += tmp;
        __syncthreads();
    }
    int pref = partials[blockIdx.x] + sh[t] - s;
    #pragma unroll
    for (int k = 0; k < 4; ++k) {
        int i = base + k;
        if (i < NN) {
            rowptr[i] = pref; cursor[i] = pref; pref += v[k];
            if (i == NN - 1) rowptr[NN] = pref;
        }
    }
}

__global__ __launch_bounds__(256) void scatter_k(const int* __restrict__ ei, int* __restrict__ cursor,
                          int* __restrict__ col) {
    int r = blockIdx.x % NR, chunk = blockIdx.x / NR;
    int lo = r * RS, hi = lo + RS;
    const int* __restrict__ dstp = ei + EE;
    int base = chunk * CE;
    int tid = threadIdx.x;
    for (int ii = 0; ii < CE; ii += 1024) {
        int d[4], s[4];
        #pragma unroll
        for (int k = 0; k < 4; ++k) {
            int off = ii + tid + k * 256;
            int i = base + off;
            d[k] = (off < CE) ? dstp[i] : -1;
            s[k] = (off < CE) ? ei[i]   : -1;
        }
        int p[4]; bool keep[4];
        #pragma unroll
        for (int k = 0; k < 4; ++k) {
            keep[k] = (d[k] >= lo && d[k] < hi && s[k] != d[k]);
            if (keep[k]) p[k] = atomicAdd(&cursor[d[k]], 1);
        }
        #pragma unroll
        for (int k = 0; k < 4; ++k) {
            if (keep[k]) col[p[k]] = s[k];
        }
    }
}

// ---------------- GEMM (h = x @ W) + per-node record ----------------
// Register-blocked 4x4 per thread. Epilogue writes an interleaved per-node
// record into Rb (stride RSU uints): [0..H) = ssrc (f32), [8..8+M/2) = h (bf16
// packed 2/uint). sdst stays a separate f32 array (only read for own node).

template<int K, int M, int H, int NPB, int RSU>
__global__ __launch_bounds__(256) void gemm_tile(const float* __restrict__ xin,
                          const float* __restrict__ W,
                          const float* __restrict__ att,
                          unsigned* __restrict__ Rb,
                          float* __restrict__ sdst) {
    constexpr int C   = M / H;
    constexpr int MG  = M / 4;               // col-groups (4 cols per thread)
    constexpr int NG  = NPB / 4;
    static_assert(MG * NG == 256, "tile mismatch");
    constexpr int K4  = K / 4;
    constexpr int KC4 = (K4 > 16) ? 16 : K4;
    constexpr int NCH = K4 / KC4;

    __shared__ float4 Wq[K * MG];
    __shared__ float4 Xq[NPB * KC4];

    int tid = threadIdx.x;
    const float4* W4 = (const float4*)W;
    for (int i = tid; i < K * MG; i += 256) Wq[i] = W4[i];

    int node0 = blockIdx.x * NPB;
    const float4* x4 = (const float4*)xin;

    int mg = tid % MG, ng = tid / MG;
    int nb = ng * 4;
    float acc[4][4];
    #pragma unroll
    for (int i = 0; i < 4; ++i)
        #pragma unroll
        for (int j = 0; j < 4; ++j) acc[i][j] = 0.f;

    for (int ch = 0; ch < NCH; ++ch) {
        __syncthreads();
        for (int i = tid; i < NPB * KC4; i += 256) {
            int n = i / KC4, k4l = i % KC4;
            int node = node0 + n;
            float4 v = make_float4(0.f, 0.f, 0.f, 0.f);
            if (node < NN) v = x4[(size_t)node * K4 + ch * KC4 + k4l];
            Xq[i] = v;
        }
        __syncthreads();
        #pragma unroll 4
        for (int k4 = 0; k4 < KC4; ++k4) {
            float4 xv[4], wv[4];
            #pragma unroll
            for (int i = 0; i < 4; ++i) xv[i] = Xq[(nb + i) * KC4 + k4];
            int kbase = (ch * KC4 + k4) * 4;
            #pragma unroll
            for (int kk = 0; kk < 4; ++kk) wv[kk] = Wq[(kbase + kk) * MG + mg];
            #pragma unroll
            for (int i = 0; i < 4; ++i) {
                const float* xf = (const float*)&xv[i];
                #pragma unroll
                for (int kk = 0; kk < 4; ++kk) {
                    const float* wf = (const float*)&wv[kk];
                    float xs = xf[kk];
                    acc[i][0] = fmaf(xs, wf[0], acc[i][0]);
                    acc[i][1] = fmaf(xs, wf[1], acc[i][1]);
                    acc[i][2] = fmaf(xs, wf[2], acc[i][2]);
                    acc[i][3] = fmaf(xs, wf[3], acc[i][3]);
                }
            }
        }
    }

    constexpr int TPH = C / 4;               // threads covering one head's cols
    int head = mg / TPH;
    int c0   = (mg % TPH) * 4;
    float ad[4], as_[4];
    #pragma unroll
    for (int j = 0; j < 4; ++j) {
        ad[j]  = att[head * 2 * C + c0 + j];
        as_[j] = att[head * 2 * C + C + c0 + j];
    }
    #pragma unroll
    for (int i = 0; i < 4; ++i) {
        int node = node0 + nb + i;
        if (node < NN) {
            unsigned short us[4];
            #pragma unroll
            for (int j = 0; j < 4; ++j) {
                __hip_bfloat16 b = __float2bfloat16(acc[i][j]);
                us[j] = *(unsigned short*)&b;
            }
            uint2 pk;
            pk.x = (unsigned)us[0] | ((unsigned)us[1] << 16);
            pk.y = (unsigned)us[2] | ((unsigned)us[3] << 16);
            *(uint2*)(Rb + (size_t)node * RSU + 8 + 2 * mg) = pk;
        }
        float pd = acc[i][0]*ad[0]  + acc[i][1]*ad[1]  + acc[i][2]*ad[2]  + acc[i][3]*ad[3];
        float ps = acc[i][0]*as_[0] + acc[i][1]*as_[1] + acc[i][2]*as_[2] + acc[i][3]*as_[3];
        #pragma unroll
        for (int off = 1; off < TPH; off <<= 1) {
            pd += __shfl_xor(pd, off, 64);
            ps += __shfl_xor(ps, off, 64);
        }
        if ((mg % TPH) == 0 && node < NN) {
            sdst[node * H + head] = pd;
            ((float*)(Rb + (size_t)node * RSU))[head] = ps;
        }
    }
}

// ---------------- Aggregation: one wave per node, U-edge masked loop ----------

template<int CT, int H, int U, int RSU, bool ELU_OUT>
__global__ __launch_bounds__(256) void agg_k(const int* __restrict__ rowptr, const int* __restrict__ col,
                      const float* __restrict__ sdst, const unsigned* __restrict__ Rb,
                      const float* __restrict__ bias, float* __restrict__ output) {
    constexpr int C    = CT / H;         // channels per head
    constexpr int CP   = CT / 2;         // lanes covering one packed row
    constexpr int G    = 64 / CP;        // edge slots per gather instruction
    constexpr int NL   = U / G;          // row gathers in flight per lane
    constexpr int EPEL = (U * H >= 64) ? (U * H) / 64 : 1;   // edges per exp lane
    static_assert(EPEL == 1 || EPEL == 2, "mapping");

    int lane = threadIdx.x & 63;
    int node = blockIdx.x * (blockDim.x >> 6) + (threadIdx.x >> 6);
    if (node >= NN) return;

    int cp = lane % CP;                  // channel pair {2cp, 2cp+1}
    int pp = lane / CP;                  // gather slot parity (0..G-1)
    int hh = (2 * cp) / C;               // head of these channels
    int eh = lane % H;                   // exp-lane head
    int gb = lane / H;                   // exp-lane base edge slot

    float sd = (lane < U * H) ? sdst[node * H + eh] : 0.f;

    int start = rowptr[node], end = rowptr[node + 1];
    int total = end + 1;                 // + virtual self-loop at index 'end'
    float2 acc = make_float2(0.f, 0.f);
    float dsum = 0.f;

    for (int j = start; j < total; j += U) {
        // cooperative col load: lane l<U covers list index j+l (clamped to node)
        int cv = node;
        {
            int idx = j + lane;
            if (lane < U && idx < end) cv = col[idx];
        }
        // exp lanes
        float e1 = 0.f, e2 = 0.f;
        if (EPEL == 2) {
            int b1 = __shfl(cv, gb, 64);
            int b2 = __shfl(cv, gb + U / 2, 64);
            float s1 = ((const float*)(Rb + (size_t)b1 * RSU))[eh];
            float s2 = ((const float*)(Rb + (size_t)b2 * RSU))[eh];
            float a1 = sd + s1; a1 = (a1 >= 0.f) ? a1 : 0.2f * a1;
            float a2 = sd + s2; a2 = (a2 >= 0.f) ? a2 : 0.2f * a2;
            if (j + gb < total)          e1 = __expf(a1);
            if (j + gb + U / 2 < total)  e2 = __expf(a2);
            dsum += e1 + e2;
        } else {
            if (lane < U * H) {
                float s1 = ((const float*)(Rb + (size_t)cv * RSU))[eh];
                float a1 = sd + s1; a1 = (a1 >= 0.f) ? a1 : 0.2f * a1;
                if (j + gb < total) e1 = __expf(a1);
                dsum += e1;
            }
        }
        // row gathers (independent, all issued before use)
        unsigned hv[NL];
        #pragma unroll
        for (int t = 0; t < NL; ++t) {
            int se = __shfl(cv, t * G + pp, 64);
            hv[t] = Rb[(size_t)se * RSU + 8 + cp];
        }
        #pragma unroll
        for (int t = 0; t < NL; ++t) {
            int eidx = t * G + pp;
            float ex;
            if (EPEL == 2)
                ex = __shfl((t < NL / 2) ? e1 : e2, (eidx & (U / 2 - 1)) * H + hh, 64);
            else
                ex = __shfl(e1, eidx * H + hh, 64);
            float hx = __uint_as_float(hv[t] << 16);
            float hy = __uint_as_float(hv[t] & 0xffff0000u);
            acc.x = fmaf(ex, hx, acc.x);
            acc.y = fmaf(ex, hy, acc.y);
        }
    }
    // reduce dsum over edge-slot lanes (masked lanes contribute 0)
    #pragma unroll
    for (int off = H; off < 64; off <<= 1) dsum += __shfl_xor(dsum, off, 64);
    float den = __shfl(dsum, hh, 64);    // lane 'hh' holds head hh's full sum
    // reduce acc over gather-slot parities
    #pragma unroll
    for (int off = CP; off < 64; off <<= 1) {
        acc.x += __shfl_xor(acc.x, off, 64);
        acc.y += __shfl_xor(acc.y, off, 64);
    }
    if (lane < CP) {
        float inv = 1.f / den;
        float vx = acc.x * inv + bias[2 * cp];
        float vy = acc.y * inv + bias[2 * cp + 1];
        if (ELU_OUT) {
            vx = (vx > 0.f) ? vx : expm1f(vx);       // ELU(alpha=1)
            vy = (vy > 0.f) ? vy : expm1f(vy);
        }
        ((float2*)output)[(size_t)node * CP + cp] = make_float2(vx, vy);
    }
}

// ---------------- launch ----------------

extern "C" void kernel_launch(void* const* d_in, const int* in_sizes, int n_in,
                              void* d_out, int out_size, void* d_ws, size_t ws_size,
                              hipStream_t stream) {
    const float* x    = (const float*)d_in[0];
    const int*   ei   = (const int*)d_in[1];
    const float* W1   = (const float*)d_in[2];
    const float* att1 = (const float*)d_in[3];
    const float* b1   = (const float*)d_in[4];
    const float* W2   = (const float*)d_in[5];
    const float* att2 = (const float*)d_in[6];
    const float* b2   = (const float*)d_in[7];
    const float* W3   = (const float*)d_in[8];
    const float* att3 = (const float*)d_in[9];
    const float* b3   = (const float*)d_in[10];
    float* out = (float*)d_out;

    char* p = (char*)d_ws;
    auto alloc = [&](size_t bytes) -> void* {
        void* r = (void*)p;
        p += (bytes + 255) & ~(size_t)255;
        return r;
    };
    int*   rowptr   = (int*)alloc((NN + 1) * sizeof(int));
    int*   cursor   = (int*)alloc(NN * sizeof(int));
    int*   partials = (int*)alloc(NB_SCAN * sizeof(int));
    int*   col      = (int*)alloc(EE * sizeof(int));
    float* sdst     = (float*)alloc((size_t)NN * 8 * sizeof(float));
    unsigned* Rb    = (unsigned*)alloc((size_t)NN * 48 * sizeof(unsigned));
    float* Fb       = (float*)alloc((size_t)NN * 64 * sizeof(float));

    // --- CSR build (dst-grouped, original non-self edges only) ---
    zero_int<<<(NN + 255) / 256, 256, 0, stream>>>(cursor, NN);
    hist_k<<<CB * NR, 256, 0, stream>>>(ei, cursor);
    sum_blocks<<<NB_SCAN, 256, 0, stream>>>(cursor, partials);
    scan_partials<<<1, 128, 0, stream>>>(partials);
    scan_final<<<NB_SCAN, 256, 0, stream>>>(cursor, partials, rowptr, cursor);
    scatter_k<<<CB * NR, 256, 0, stream>>>(ei, cursor, col);

    // --- Layer 1: x[N,128] -> h[N,64]; H=8, C=8; ELU out -> Fb ---
    gemm_tile<128, 64, 8, 64, 48><<<(NN + 63) / 64, 256, 0, stream>>>(x, W1, att1, Rb, sdst);
    agg_k<64, 8, 16, 48, true><<<(NN + 3) / 4, 256, 0, stream>>>(rowptr, col, sdst, Rb, b1, Fb);

    // --- Layer 2: Fb[N,64] -> h[N,64]; H=8, C=8; ELU out -> Fb ---
    gemm_tile<64, 64, 8, 64, 48><<<(NN + 63) / 64, 256, 0, stream>>>(Fb, W2, att2, Rb, sdst);
    agg_k<64, 8, 16, 48, true><<<(NN + 3) / 4, 256, 0, stream>>>(rowptr, col, sdst, Rb, b2, Fb);

    // --- Layer 3: Fb[N,64] -> h[N,32]; H=1, C=32; no ELU, f32 out -> d_out ---
    gemm_tile<64, 32, 1, 128, 32><<<(NN + 127) / 128, 256, 0, stream>>>(Fb, W3, att3, Rb, sdst);
    agg_k<32, 1, 32, 32, false><<<(NN + 3) / 4, 256, 0, stream>>>(rowptr, col, sdst, Rb, b3, out);
}

// Round 9
// 450.041 us; speedup vs baseline: 1.0995x; 1.0995x over previous
//
#include <hip/hip_runtime.h>
#include <hip/hip_bf16.h>

#define NN 100000
#define EE 1600000

constexpr int SCAN_BLK = 1024;                       // elements per scan block (256 thr * 4)
constexpr int NB_SCAN  = (NN + SCAN_BLK - 1) / SCAN_BLK;  // 98

// Range-partitioned scatter: 8 dst-ranges
constexpr int NR  = 8;
constexpr int RS  = NN / NR;        // 12500 nodes per range
constexpr int CB  = 200;            // edge chunks
constexpr int CE  = EE / CB;        // 8000 edges per chunk (exact)

// ---------------- CSR build ----------------

__global__ void zero_int(int* __restrict__ p, int n) {
    int i = blockIdx.x * 256 + threadIdx.x;
    if (i < n) p[i] = 0;
}

// Phase A: single pass over all edges. Full-density atomics (no range filter),
// rank written back COALESCED -> no random store after the atomic.
__global__ __launch_bounds__(256) void hist_rank_k(const int* __restrict__ ei,
                                                   int* __restrict__ deg,
                                                   int* __restrict__ rank) {
    int base = blockIdx.x * 1024;
    const int* __restrict__ dstp = ei + EE;
    int tid = threadIdx.x;
    int d[4], s[4], r[4];
    #pragma unroll
    for (int k = 0; k < 4; ++k) {
        int off = base + tid + k * 256;
        bool v = off < EE;
        d[k] = v ? dstp[off] : -1;
        s[k] = v ? ei[off]   : -1;
        r[k] = 0;
    }
    #pragma unroll
    for (int k = 0; k < 4; ++k) {
        if (d[k] >= 0 && s[k] != d[k]) r[k] = atomicAdd(&deg[d[k]], 1);
    }
    #pragma unroll
    for (int k = 0; k < 4; ++k) {
        int off = base + tid + k * 256;
        if (off < EE) rank[off] = r[k];
    }
}

__global__ void sum_blocks(const int* __restrict__ deg, int* __restrict__ partials) {
    __shared__ int sh[256];
    int t = threadIdx.x;
    int base = blockIdx.x * SCAN_BLK + t * 4;
    int s = 0;
    #pragma unroll
    for (int k = 0; k < 4; ++k) { int i = base + k; if (i < NN) s += deg[i]; }
    sh[t] = s; __syncthreads();
    for (int off = 128; off > 0; off >>= 1) {
        if (t < off) sh[t] += sh[t + off];
        __syncthreads();
    }
    if (t == 0) partials[blockIdx.x] = sh[0];
}

__global__ void scan_partials(int* __restrict__ partials) {
    __shared__ int sh[128];
    int t = threadIdx.x;
    int v = (t < NB_SCAN) ? partials[t] : 0;
    sh[t] = v;
    __syncthreads();
    for (int off = 1; off < 128; off <<= 1) {
        int tmp = (t >= off) ? sh[t - off] : 0;
        __syncthreads();
        sh[t] += tmp;
        __syncthreads();
    }
    if (t < NB_SCAN) partials[t] = sh[t] - v;   // exclusive prefix
}

__global__ void scan_final(const int* __restrict__ deg, const int* __restrict__ partials,
                           int* __restrict__ rowptr) {
    __shared__ int sh[256];
    int t = threadIdx.x;
    int base = blockIdx.x * SCAN_BLK + t * 4;
    int v[4]; int s = 0;
    #pragma unroll
    for (int k = 0; k < 4; ++k) { int i = base + k; v[k] = (i < NN) ? deg[i] : 0; s += v[k]; }
    sh[t] = s; __syncthreads();
    for (int off = 1; off < 256; off <<= 1) {
        int tmp = (t >= off) ? sh[t - off] : 0;
        __syncthreads();
        sh[t] += tmp;
        __syncthreads();
    }
    int pref = partials[blockIdx.x] + sh[t] - s;
    #pragma unroll
    for (int k = 0; k < 4; ++k) {
        int i = base + k;
        if (i < NN) {
            rowptr[i] = pref; pref += v[k];
            if (i == NN - 1) rowptr[NN] = pref;
        }
    }
}

// Phase C: no atomics. p = rowptr[d] + rank[e] (random L2 read), col[p] = s.
// Range partitioning keeps the random reads/writes in a small slice.
__global__ __launch_bounds__(256) void scatter2_k(const int* __restrict__ ei,
                                                  const int* __restrict__ rank,
                                                  const int* __restrict__ rowptr,
                                                  int* __restrict__ col) {
    int rg = blockIdx.x % NR, chunk = blockIdx.x / NR;
    int lo = rg * RS, hi = lo + RS;
    const int* __restrict__ dstp = ei + EE;
    int base = chunk * CE;
    int tid = threadIdx.x;
    for (int ii = 0; ii < CE; ii += 1024) {
        int d[4], s[4], rk[4];
        #pragma unroll
        for (int k = 0; k < 4; ++k) {
            int off = ii + tid + k * 256;
            int i = base + off;
            bool v = off < CE;
            d[k]  = v ? dstp[i] : -1;
            s[k]  = v ? ei[i]   : -1;
            rk[k] = v ? rank[i] : 0;
        }
        int p[4]; bool keep[4];
        #pragma unroll
        for (int k = 0; k < 4; ++k) {
            keep[k] = (d[k] >= lo && d[k] < hi && s[k] != d[k]);
            if (keep[k]) p[k] = rowptr[d[k]] + rk[k];
        }
        #pragma unroll
        for (int k = 0; k < 4; ++k) {
            if (keep[k]) col[p[k]] = s[k];
        }
    }
}

// ---------------- GEMM (h = x @ W) + per-node record ----------------
// Register-blocked 4x4 per thread. Epilogue writes an interleaved per-node
// record into Rb (stride RSU uints): [0..H) = ssrc (f32), [8..8+M/2) = h (bf16
// packed 2/uint). sdst stays a separate f32 array (only read for own node).

template<int K, int M, int H, int NPB, int RSU>
__global__ __launch_bounds__(256) void gemm_tile(const float* __restrict__ xin,
                          const float* __restrict__ W,
                          const float* __restrict__ att,
                          unsigned* __restrict__ Rb,
                          float* __restrict__ sdst) {
    constexpr int C   = M / H;
    constexpr int MG  = M / 4;               // col-groups (4 cols per thread)
    constexpr int NG  = NPB / 4;
    static_assert(MG * NG == 256, "tile mismatch");
    constexpr int K4  = K / 4;
    constexpr int KC4 = (K4 > 16) ? 16 : K4;
    constexpr int NCH = K4 / KC4;

    __shared__ float4 Wq[K * MG];
    __shared__ float4 Xq[NPB * KC4];

    int tid = threadIdx.x;
    const float4* W4 = (const float4*)W;
    for (int i = tid; i < K * MG; i += 256) Wq[i] = W4[i];

    int node0 = blockIdx.x * NPB;
    const float4* x4 = (const float4*)xin;

    int mg = tid % MG, ng = tid / MG;
    int nb = ng * 4;
    float acc[4][4];
    #pragma unroll
    for (int i = 0; i < 4; ++i)
        #pragma unroll
        for (int j = 0; j < 4; ++j) acc[i][j] = 0.f;

    for (int ch = 0; ch < NCH; ++ch) {
        __syncthreads();
        for (int i = tid; i < NPB * KC4; i += 256) {
            int n = i / KC4, k4l = i % KC4;
            int node = node0 + n;
            float4 v = make_float4(0.f, 0.f, 0.f, 0.f);
            if (node < NN) v = x4[(size_t)node * K4 + ch * KC4 + k4l];
            Xq[i] = v;
        }
        __syncthreads();
        #pragma unroll 4
        for (int k4 = 0; k4 < KC4; ++k4) {
            float4 xv[4], wv[4];
            #pragma unroll
            for (int i = 0; i < 4; ++i) xv[i] = Xq[(nb + i) * KC4 + k4];
            int kbase = (ch * KC4 + k4) * 4;
            #pragma unroll
            for (int kk = 0; kk < 4; ++kk) wv[kk] = Wq[(kbase + kk) * MG + mg];
            #pragma unroll
            for (int i = 0; i < 4; ++i) {
                const float* xf = (const float*)&xv[i];
                #pragma unroll
                for (int kk = 0; kk < 4; ++kk) {
                    const float* wf = (const float*)&wv[kk];
                    float xs = xf[kk];
                    acc[i][0] = fmaf(xs, wf[0], acc[i][0]);
                    acc[i][1] = fmaf(xs, wf[1], acc[i][1]);
                    acc[i][2] = fmaf(xs, wf[2], acc[i][2]);
                    acc[i][3] = fmaf(xs, wf[3], acc[i][3]);
                }
            }
        }
    }

    constexpr int TPH = C / 4;               // threads covering one head's cols
    int head = mg / TPH;
    int c0   = (mg % TPH) * 4;
    float ad[4], as_[4];
    #pragma unroll
    for (int j = 0; j < 4; ++j) {
        ad[j]  = att[head * 2 * C + c0 + j];
        as_[j] = att[head * 2 * C + C + c0 + j];
    }
    #pragma unroll
    for (int i = 0; i < 4; ++i) {
        int node = node0 + nb + i;
        if (node < NN) {
            unsigned short us[4];
            #pragma unroll
            for (int j = 0; j < 4; ++j) {
                __hip_bfloat16 b = __float2bfloat16(acc[i][j]);
                us[j] = *(unsigned short*)&b;
            }
            uint2 pk;
            pk.x = (unsigned)us[0] | ((unsigned)us[1] << 16);
            pk.y = (unsigned)us[2] | ((unsigned)us[3] << 16);
            *(uint2*)(Rb + (size_t)node * RSU + 8 + 2 * mg) = pk;
        }
        float pd = acc[i][0]*ad[0]  + acc[i][1]*ad[1]  + acc[i][2]*ad[2]  + acc[i][3]*ad[3];
        float ps = acc[i][0]*as_[0] + acc[i][1]*as_[1] + acc[i][2]*as_[2] + acc[i][3]*as_[3];
        #pragma unroll
        for (int off = 1; off < TPH; off <<= 1) {
            pd += __shfl_xor(pd, off, 64);
            ps += __shfl_xor(ps, off, 64);
        }
        if ((mg % TPH) == 0 && node < NN) {
            sdst[node * H + head] = pd;
            ((float*)(Rb + (size_t)node * RSU))[head] = ps;
        }
    }
}

// ---------------- Aggregation: one wave per node, U-edge masked loop ----------

template<int CT, int H, int U, int RSU, bool ELU_OUT>
__global__ __launch_bounds__(256) void agg_k(const int* __restrict__ rowptr, const int* __restrict__ col,
                      const float* __restrict__ sdst, const unsigned* __restrict__ Rb,
                      const float* __restrict__ bias, float* __restrict__ output) {
    constexpr int C    = CT / H;         // channels per head
    constexpr int CP   = CT / 2;         // lanes covering one packed row
    constexpr int G    = 64 / CP;        // edge slots per gather instruction
    constexpr int NL   = U / G;          // row gathers in flight per lane
    constexpr int EPEL = (U * H >= 64) ? (U * H) / 64 : 1;   // edges per exp lane
    static_assert(EPEL == 1 || EPEL == 2, "mapping");

    int lane = threadIdx.x & 63;
    int node = blockIdx.x * (blockDim.x >> 6) + (threadIdx.x >> 6);
    if (node >= NN) return;

    int cp = lane % CP;                  // channel pair {2cp, 2cp+1}
    int pp = lane / CP;                  // gather slot parity (0..G-1)
    int hh = (2 * cp) / C;               // head of these channels
    int eh = lane % H;                   // exp-lane head
    int gb = lane / H;                   // exp-lane base edge slot

    float sd = (lane < U * H) ? sdst[node * H + eh] : 0.f;

    int start = rowptr[node], end = rowptr[node + 1];
    int total = end + 1;                 // + virtual self-loop at index 'end'
    float2 acc = make_float2(0.f, 0.f);
    float dsum = 0.f;

    for (int j = start; j < total; j += U) {
        // cooperative col load: lane l<U covers list index j+l (clamped to node)
        int cv = node;
        {
            int idx = j + lane;
            if (lane < U && idx < end) cv = col[idx];
        }
        // exp lanes
        float e1 = 0.f, e2 = 0.f;
        if (EPEL == 2) {
            int b1 = __shfl(cv, gb, 64);
            int b2 = __shfl(cv, gb + U / 2, 64);
            float s1 = ((const float*)(Rb + (size_t)b1 * RSU))[eh];
            float s2 = ((const float*)(Rb + (size_t)b2 * RSU))[eh];
            float a1 = sd + s1; a1 = (a1 >= 0.f) ? a1 : 0.2f * a1;
            float a2 = sd + s2; a2 = (a2 >= 0.f) ? a2 : 0.2f * a2;
            if (j + gb < total)          e1 = __expf(a1);
            if (j + gb + U / 2 < total)  e2 = __expf(a2);
            dsum += e1 + e2;
        } else {
            if (lane < U * H) {
                float s1 = ((const float*)(Rb + (size_t)cv * RSU))[eh];
                float a1 = sd + s1; a1 = (a1 >= 0.f) ? a1 : 0.2f * a1;
                if (j + gb < total) e1 = __expf(a1);
                dsum += e1;
            }
        }
        // row gathers (independent, all issued before use)
        unsigned hv[NL];
        #pragma unroll
        for (int t = 0; t < NL; ++t) {
            int se = __shfl(cv, t * G + pp, 64);
            hv[t] = Rb[(size_t)se * RSU + 8 + cp];
        }
        #pragma unroll
        for (int t = 0; t < NL; ++t) {
            int eidx = t * G + pp;
            float ex;
            if (EPEL == 2)
                ex = __shfl((t < NL / 2) ? e1 : e2, (eidx & (U / 2 - 1)) * H + hh, 64);
            else
                ex = __shfl(e1, eidx * H + hh, 64);
            float hx = __uint_as_float(hv[t] << 16);
            float hy = __uint_as_float(hv[t] & 0xffff0000u);
            acc.x = fmaf(ex, hx, acc.x);
            acc.y = fmaf(ex, hy, acc.y);
        }
    }
    // reduce dsum over edge-slot lanes (masked lanes contribute 0)
    #pragma unroll
    for (int off = H; off < 64; off <<= 1) dsum += __shfl_xor(dsum, off, 64);
    float den = __shfl(dsum, hh, 64);    // lane 'hh' holds head hh's full sum
    // reduce acc over gather-slot parities
    #pragma unroll
    for (int off = CP; off < 64; off <<= 1) {
        acc.x += __shfl_xor(acc.x, off, 64);
        acc.y += __shfl_xor(acc.y, off, 64);
    }
    if (lane < CP) {
        float inv = 1.f / den;
        float vx = acc.x * inv + bias[2 * cp];
        float vy = acc.y * inv + bias[2 * cp + 1];
        if (ELU_OUT) {
            vx = (vx > 0.f) ? vx : expm1f(vx);       // ELU(alpha=1)
            vy = (vy > 0.f) ? vy : expm1f(vy);
        }
        ((float2*)output)[(size_t)node * CP + cp] = make_float2(vx, vy);
    }
}

// ---------------- launch ----------------

extern "C" void kernel_launch(void* const* d_in, const int* in_sizes, int n_in,
                              void* d_out, int out_size, void* d_ws, size_t ws_size,
                              hipStream_t stream) {
    const float* x    = (const float*)d_in[0];
    const int*   ei   = (const int*)d_in[1];
    const float* W1   = (const float*)d_in[2];
    const float* att1 = (const float*)d_in[3];
    const float* b1   = (const float*)d_in[4];
    const float* W2   = (const float*)d_in[5];
    const float* att2 = (const float*)d_in[6];
    const float* b2   = (const float*)d_in[7];
    const float* W3   = (const float*)d_in[8];
    const float* att3 = (const float*)d_in[9];
    const float* b3   = (const float*)d_in[10];
    float* out = (float*)d_out;

    char* p = (char*)d_ws;
    auto alloc = [&](size_t bytes) -> void* {
        void* r = (void*)p;
        p += (bytes + 255) & ~(size_t)255;
        return r;
    };
    int*   rowptr   = (int*)alloc((NN + 1) * sizeof(int));
    int*   deg      = (int*)alloc(NN * sizeof(int));
    int*   partials = (int*)alloc(NB_SCAN * sizeof(int));
    int*   col      = (int*)alloc(EE * sizeof(int));
    int*   rank     = (int*)alloc(EE * sizeof(int));
    float* sdst     = (float*)alloc((size_t)NN * 8 * sizeof(float));
    unsigned* Rb    = (unsigned*)alloc((size_t)NN * 48 * sizeof(unsigned));
    float* Fb       = (float*)alloc((size_t)NN * 64 * sizeof(float));

    // --- CSR build (dst-grouped, original non-self edges only) ---
    zero_int<<<(NN + 255) / 256, 256, 0, stream>>>(deg, NN);
    hist_rank_k<<<(EE + 1023) / 1024, 256, 0, stream>>>(ei, deg, rank);
    sum_blocks<<<NB_SCAN, 256, 0, stream>>>(deg, partials);
    scan_partials<<<1, 128, 0, stream>>>(partials);
    scan_final<<<NB_SCAN, 256, 0, stream>>>(deg, partials, rowptr);
    scatter2_k<<<CB * NR, 256, 0, stream>>>(ei, rank, rowptr, col);

    // --- Layer 1: x[N,128] -> h[N,64]; H=8, C=8; ELU out -> Fb ---
    gemm_tile<128, 64, 8, 64, 48><<<(NN + 63) / 64, 256, 0, stream>>>(x, W1, att1, Rb, sdst);
    agg_k<64, 8, 16, 48, true><<<(NN + 3) / 4, 256, 0, stream>>>(rowptr, col, sdst, Rb, b1, Fb);

    // --- Layer 2: Fb[N,64] -> h[N,64]; H=8, C=8; ELU out -> Fb ---
    gemm_tile<64, 64, 8, 64, 48><<<(NN + 63) / 64, 256, 0, stream>>>(Fb, W2, att2, Rb, sdst);
    agg_k<64, 8, 16, 48, true><<<(NN + 3) / 4, 256, 0, stream>>>(rowptr, col, sdst, Rb, b2, Fb);

    // --- Layer 3: Fb[N,64] -> h[N,32]; H=1, C=32; no ELU, f32 out -> d_out ---
    gemm_tile<64, 32, 1, 128, 32><<<(NN + 127) / 128, 256, 0, stream>>>(Fb, W3, att3, Rb, sdst);
    agg_k<32, 1, 32, 32, false><<<(NN + 3) / 4, 256, 0, stream>>>(rowptr, col, sdst, Rb, b3, out);
}